// Round 16
// baseline (1100.497 us; speedup 1.0000x reference)
//
#include <hip/hip_runtime.h>

constexpr int IN   = 256;
constexpr int H    = 256;
constexpr int STR  = 60;
constexpr int NLOC = 8;
constexpr int CW   = 32;      // columns per state slab (8 slabs of 32 cols = 64B line)
constexpr int KP   = 288;     // padded K for MFMA (264 -> 288)
constexpr int CAP  = 96;      // fixed CSR row capacity; band0 front (<=48), band1 back (<=48)
constexpr int BC   = 48;      // per-band cap
constexpr int BSTR = 40;      // LDS B-stage col stride (ushorts)

typedef float    f32x4 __attribute__((ext_vector_type(4)));
typedef unsigned u32x2 __attribute__((ext_vector_type(2)));
typedef short    bf16x8 __attribute__((ext_vector_type(8)));

__device__ __forceinline__ float bflo(unsigned u) { return __uint_as_float(u << 16); }
__device__ __forceinline__ float bfhi(unsigned u) { return __uint_as_float(u & 0xFFFF0000u); }
__device__ __forceinline__ unsigned short f2bf(float f) {
  unsigned u = __float_as_uint(f);
  u += 0x7FFF + ((u >> 16) & 1);          // round-to-nearest-even
  return (unsigned short)(u >> 16);
}

// ---------------- pos_embedding (also zeroes cnt0/cnt1) ----------------
__global__ void k_pe(const float* __restrict__ pos_emb, const float* __restrict__ lap_pe,
                     const float* __restrict__ W, const float* __restrict__ b,
                     float* __restrict__ pe, int* __restrict__ cnt0,
                     int* __restrict__ cnt1, int n) {
  int i = blockIdx.x*blockDim.x + threadIdx.x;
  if (i >= n) return;
  cnt0[i] = 0; cnt1[i] = 0;
  float acc[NLOC];
  #pragma unroll
  for (int j = 0; j < NLOC; ++j) acc[j] = b[j];
  const float* pr = pos_emb + (size_t)i*STR;
  for (int k = 0; k < STR; ++k) {
    float v = pr[k];
    #pragma unroll
    for (int j = 0; j < NLOC; ++j) acc[j] += v*W[k*NLOC + j];
  }
  const float* lr = lap_pe + (size_t)i*(STR-1);
  for (int k = 0; k < STR-1; ++k) {
    float v = lr[k];
    #pragma unroll
    for (int j = 0; j < NLOC; ++j) acc[j] += v*W[(STR+k)*NLOC + j];
  }
  float* po = pe + (size_t)i*NLOC;
  #pragma unroll
  for (int j = 0; j < NLOC; ++j) po[j] = acc[j];
}

// ---------------- W transpose+convert: Wtb[col][KP] bf16, zero-padded ----------------
__global__ void k_wtb(const float* __restrict__ W, unsigned short* __restrict__ Wtb) {
  int col = blockIdx.x;                 // 0..255
  for (int k = threadIdx.x; k < KP; k += blockDim.x) {
    float v = (k < IN + NLOC) ? W[(size_t)k*H + col] : 0.f;
    Wtb[(size_t)col*KP + k] = f2bf(v);
  }
}

// ---------------- XCD-partitioned scatter; band0 front-fill, band1 back-fill ----------------
__global__ void k_scatter(const int* __restrict__ row, const int* __restrict__ col,
                          int* __restrict__ cnt0, int* __restrict__ cnt1,
                          int* __restrict__ colbuf, int E, int rpx, int nhalf) {
  int xcd = blockIdx.x & 7;
  int rlo = xcd * rpx;
  int rhi = rlo + rpx;
  int nblk = gridDim.x >> 3;
  int bi = blockIdx.x >> 3;
  int stride = (nblk * blockDim.x) << 2;
  int i0 = (bi*blockDim.x + threadIdx.x) << 2;
  for (int i = i0; i + 4 <= E; i += stride) {
    int4 rr = *(const int4*)&row[i];
    #pragma unroll
    for (int u = 0; u < 4; ++u) {
      int r = (u==0)?rr.x:(u==1)?rr.y:(u==2)?rr.z:rr.w;
      if (r >= rlo && r < rhi) {
        int c = col[i+u];
        if (c < nhalf) {
          int p = atomicAdd(&cnt0[r], 1);
          if (p < BC) colbuf[(size_t)r*CAP + p] = c;
        } else {
          int p = atomicAdd(&cnt1[r], 1);
          if (p < BC) colbuf[(size_t)r*CAP + (CAP-1) - p] = c;
        }
      }
    }
  }
  if (blockIdx.x == 0 && threadIdx.x < 4) {
    int base = E & ~3;
    int i = base + threadIdx.x;
    if (i < E) {
      int r = row[i];
      if (r >= rlo && r < rhi) {
        int c = col[i];
        if (c < nhalf) {
          int p = atomicAdd(&cnt0[r], 1);
          if (p < BC) colbuf[(size_t)r*CAP + p] = c;
        } else {
          int p = atomicAdd(&cnt1[r], 1);
          if (p < BC) colbuf[(size_t)r*CAP + (CAP-1) - p] = c;
        }
      }
    }
  }
}

// ---------------- norm + rnorm from counts ----------------
__global__ void k_norm(const int* __restrict__ cnt0, const int* __restrict__ cnt1,
                       float* __restrict__ norm, float* __restrict__ rnorm, int n) {
  int i = blockIdx.x*blockDim.x + threadIdx.x;
  if (i >= n) return;
  int d0 = cnt0[i]; if (d0 > BC) d0 = BC;
  int d1 = cnt1[i]; if (d1 > BC) d1 = BC;
  float s = 1.0f + (float)(d0 + d1);
  norm[i]  = rsqrtf(s);
  rnorm[i] = sqrtf(s);
}

// ---------------- xemb via MFMA bf16, LDS-staged B (R15-proven), 8-slab output ----------------
__global__ __launch_bounds__(256) void k_xemb(
    const float* __restrict__ x, const float* __restrict__ pe,
    const unsigned short* __restrict__ Wtb, const float* __restrict__ bvec,
    const float* __restrict__ norm, unsigned short* __restrict__ st, int n) {
  __shared__ unsigned short Bs[256*BSTR];    // 20 KB
  int t = threadIdx.x;
  int wv = t >> 6, l = t & 63;
  int lr = l & 15, kb = l >> 4;
  int i0 = blockIdx.x*64 + wv*16;
  int arow = i0 + lr;
  int ar = (arow < n) ? arow : n - 1;

  f32x4 acc[16];
  #pragma unroll
  for (int cb = 0; cb < 16; ++cb) acc[cb] = (f32x4){0.f,0.f,0.f,0.f};

  #pragma unroll
  for (int ks = 0; ks < 9; ++ks) {
    int k0 = ks*32;
    __syncthreads();
    {
      const unsigned short* wsrc = Wtb + (size_t)t*KP + k0;
      unsigned short* wdst = Bs + t*BSTR;
      #pragma unroll
      for (int m = 0; m < 4; ++m)
        *(bf16x8*)(wdst + m*8) = *(const bf16x8*)(wsrc + m*8);
    }
    float a8[8];
    if (ks < 8) {
      const float* ap = x + (size_t)ar*IN + k0 + kb*8;
      float4 v0 = *(const float4*)ap;
      float4 v1 = *(const float4*)(ap + 4);
      a8[0]=v0.x; a8[1]=v0.y; a8[2]=v0.z; a8[3]=v0.w;
      a8[4]=v1.x; a8[5]=v1.y; a8[6]=v1.z; a8[7]=v1.w;
    } else if (kb == 0) {
      const float* ap = pe + (size_t)ar*NLOC;
      float4 v0 = *(const float4*)ap;
      float4 v1 = *(const float4*)(ap + 4);
      a8[0]=v0.x; a8[1]=v0.y; a8[2]=v0.z; a8[3]=v0.w;
      a8[4]=v1.x; a8[5]=v1.y; a8[6]=v1.z; a8[7]=v1.w;
    } else {
      #pragma unroll
      for (int j = 0; j < 8; ++j) a8[j] = 0.f;
    }
    bf16x8 af;
    #pragma unroll
    for (int j = 0; j < 8; ++j) af[j] = (short)f2bf(a8[j]);
    __syncthreads();
    #pragma unroll
    for (int cb = 0; cb < 16; ++cb) {
      bf16x8 bf = *(const bf16x8*)(Bs + (cb*16 + lr)*BSTR + kb*8);
      acc[cb] = __builtin_amdgcn_mfma_f32_16x16x32_bf16(af, bf, acc[cb], 0, 0, 0);
    }
  }

  int r0 = i0 + kb*4;
  float nrm[4];
  #pragma unroll
  for (int j = 0; j < 4; ++j) {
    int rr = r0 + j;
    nrm[j] = (rr < n) ? norm[rr] : 0.f;
  }
  size_t slabsz = (size_t)n * CW;
  #pragma unroll
  for (int cb = 0; cb < 16; ++cb) {
    int col = cb*16 + lr;
    float bias = bvec[col];
    unsigned short* sp = st + (size_t)(col >> 5)*slabsz + (col & 31);
    #pragma unroll
    for (int j = 0; j < 4; ++j) {
      int rr = r0 + j;
      if (rr < n)
        sp[(size_t)rr*CW] = f2bf(nrm[j]*(acc[cb][j] + bias));
    }
  }
}

// ---------------- layer pass 0: partial = bf16( sum over band0 edges ) ----------------
// 8-slab; chunk = blockIdx&7 (XCD-affine); wave = 8 rows x 8 lanes x uint2.
__global__ __launch_bounds__(256) void k_p0(
    const unsigned short* __restrict__ st, const int* __restrict__ cnt0,
    const int* __restrict__ colbuf, unsigned short* __restrict__ partial,
    int n) {
  int w = blockIdx.x;
  int chunk = w & 7;
  int rb = w >> 3;
  int t = threadIdx.x;
  int wave = t >> 6, lane = t & 63;
  int li = lane & 7, rs = lane >> 3;
  int r = rb*32 + wave*8 + rs;
  if (r >= n) return;
  size_t slabu2 = (size_t)n * 8;         // uint2 per slab (32 cols = 8 uint2)
  const uint2* gb = (const uint2*)st + (size_t)chunk*slabu2 + li;
  int c0 = cnt0[r]; if (c0 > BC) c0 = BC;
  int start = r*CAP, end = start + c0;
  float4 acc = make_float4(0.f,0.f,0.f,0.f);
  int j = start;
  for (; j + 4 <= end; j += 4) {
    int4 cc = *(const int4*)&colbuf[j];
    uint2 v0 = gb[(size_t)cc.x*8];
    uint2 v1 = gb[(size_t)cc.y*8];
    uint2 v2 = gb[(size_t)cc.z*8];
    uint2 v3 = gb[(size_t)cc.w*8];
    acc.x += (bflo(v0.x)+bflo(v1.x)) + (bflo(v2.x)+bflo(v3.x));
    acc.y += (bfhi(v0.x)+bfhi(v1.x)) + (bfhi(v2.x)+bfhi(v3.x));
    acc.z += (bflo(v0.y)+bflo(v1.y)) + (bflo(v2.y)+bflo(v3.y));
    acc.w += (bfhi(v0.y)+bfhi(v1.y)) + (bfhi(v2.y)+bfhi(v3.y));
  }
  for (; j < end; ++j) {
    int c0i = colbuf[j];
    uint2 v0 = gb[(size_t)c0i*8];
    acc.x += bflo(v0.x); acc.y += bfhi(v0.x);
    acc.z += bflo(v0.y); acc.w += bfhi(v0.y);
  }
  unsigned short s0 = f2bf(acc.x);
  unsigned short s1 = f2bf(acc.y);
  unsigned short s2 = f2bf(acc.z);
  unsigned short s3 = f2bf(acc.w);
  u32x2 pk;
  pk.x = (unsigned)s0 | ((unsigned)s1 << 16);
  pk.y = (unsigned)s2 | ((unsigned)s3 << 16);
  __builtin_nontemporal_store(pk,
      (u32x2*)partial + (size_t)chunk*slabu2 + (size_t)r*8 + li);
}

// ---------------- layer pass 1: band1 + partial + self -> st_next / fused JK out ----------------
__global__ __launch_bounds__(256) void k_p1(
    const unsigned short* __restrict__ st, const int* __restrict__ cnt1,
    const int* __restrict__ colbuf, const unsigned short* __restrict__ partial,
    const float* __restrict__ norm, unsigned short* __restrict__ st_next, int last,
    const unsigned short* __restrict__ s0buf, const unsigned short* __restrict__ s1buf,
    const float* __restrict__ rnorm, const float* __restrict__ jkp,
    float* __restrict__ out, int n) {
  int w = blockIdx.x;
  int chunk = w & 7;
  int rb = w >> 3;
  int t = threadIdx.x;
  int wave = t >> 6, lane = t & 63;
  int li = lane & 7, rs = lane >> 3;
  int r = rb*32 + wave*8 + rs;
  if (r >= n) return;
  size_t slabu2 = (size_t)n * 8;
  const uint2* gb = (const uint2*)st + (size_t)chunk*slabu2 + li;
  int c1 = cnt1[r]; if (c1 > BC) c1 = BC;
  int base = r*CAP;
  int start = base + CAP - c1, end = base + CAP;
  float4 acc = make_float4(0.f,0.f,0.f,0.f);
  int j = start;
  for (; j + 2 <= end; j += 2) {
    int ca = colbuf[j], cb2 = colbuf[j+1];
    uint2 v0 = gb[(size_t)ca*8];
    uint2 v1 = gb[(size_t)cb2*8];
    acc.x += bflo(v0.x)+bflo(v1.x); acc.y += bfhi(v0.x)+bfhi(v1.x);
    acc.z += bflo(v0.y)+bflo(v1.y); acc.w += bfhi(v0.y)+bfhi(v1.y);
  }
  if (j < end) {
    int ca = colbuf[j];
    uint2 v0 = gb[(size_t)ca*8];
    acc.x += bflo(v0.x); acc.y += bfhi(v0.x);
    acc.z += bflo(v0.y); acc.w += bfhi(v0.y);
  }
  size_t off = (size_t)chunk*slabu2 + (size_t)r*8 + li;
  // band0 partial
  uint2 pv = ((const uint2*)partial)[off];
  acc.x += bflo(pv.x); acc.y += bfhi(pv.x);
  acc.z += bflo(pv.y); acc.w += bfhi(pv.y);
  // self term
  uint2 sv = gb[(size_t)r*8];
  acc.x += bflo(sv.x); acc.y += bfhi(sv.x);
  acc.z += bflo(sv.y); acc.w += bfhi(sv.y);
  float nr = norm[r];
  float n2 = nr*nr;
  if (!last) {
    unsigned short s0 = f2bf(n2*acc.x);
    unsigned short s1 = f2bf(n2*acc.y);
    unsigned short s2 = f2bf(n2*acc.z);
    unsigned short s3 = f2bf(n2*acc.w);
    u32x2 pk;
    pk.x = (unsigned)s0 | ((unsigned)s1 << 16);
    pk.y = (unsigned)s2 | ((unsigned)s3 << 16);
    __builtin_nontemporal_store(pk, (u32x2*)st_next + off);
  } else {
    uint2 a = ((const uint2*)s0buf)[off];
    uint2 b = ((const uint2*)s1buf)[off];
    float rn = rnorm[r];
    float j0 = jkp[0], j1 = jkp[1], j2 = jkp[2];
    f32x4 o;
    o.x = rn*(j0*bflo(a.x) + j1*bflo(b.x) + j2*(n2*acc.x));
    o.y = rn*(j0*bfhi(a.x) + j1*bfhi(b.x) + j2*(n2*acc.y));
    o.z = rn*(j0*bflo(a.y) + j1*bflo(b.y) + j2*(n2*acc.z));
    o.w = rn*(j0*bfhi(a.y) + j1*bfhi(b.y) + j2*(n2*acc.w));
    __builtin_nontemporal_store(o, (f32x4*)(out + (size_t)r*H + chunk*CW + li*4));
  }
}

extern "C" void kernel_launch(void* const* d_in, const int* in_sizes, int n_in,
                              void* d_out, int out_size, void* d_ws, size_t ws_size,
                              hipStream_t stream) {
  const float* x       = (const float*)d_in[0];
  const float* pos_emb = (const float*)d_in[1];
  const float* lap_pe  = (const float*)d_in[2];
  const float* W_pos   = (const float*)d_in[3];
  const float* b_pos   = (const float*)d_in[4];
  const float* W_xemb  = (const float*)d_in[5];
  const float* b_xemb  = (const float*)d_in[6];
  const float* jkp     = (const float*)d_in[7];
  const int*   row     = (const int*)d_in[8];
  const int*   col     = (const int*)d_in[9];
  int N = in_sizes[0] / IN;
  int E = in_sizes[8];
  float* out = (float*)d_out;

  char* p = (char*)d_ws;
  auto alloc = [&](size_t bytes) {
    char* r = p; p += (bytes + 255) & ~(size_t)255; return r;
  };
  unsigned short* bfA     = (unsigned short*)alloc((size_t)N*H*2);  // xemb / st1
  unsigned short* st0     = (unsigned short*)alloc((size_t)N*H*2);  // layer0 out
  unsigned short* partial = (unsigned short*)alloc((size_t)N*H*2);  // band0 partial
  int*   colbuf = (int*)  alloc((size_t)N*CAP*4);                   // 38.4 MB
  float* pe     = (float*)alloc((size_t)N*NLOC*4);
  int*   cnt0   = (int*)  alloc((size_t)N*4);
  int*   cnt1   = (int*)  alloc((size_t)N*4);
  float* norm   = (float*)alloc((size_t)N*4);
  float* rnorm  = (float*)alloc((size_t)N*4);
  unsigned short* Wtb = (unsigned short*)alloc((size_t)H*KP*2);

  int nhalf = (N + 1) >> 1;

  k_pe<<<(N+255)/256, 256, 0, stream>>>(pos_emb, lap_pe, W_pos, b_pos, pe, cnt0, cnt1, N);
  k_wtb<<<H, 128, 0, stream>>>(W_xemb, Wtb);
  int rpx = (N + 7)/8;
  k_scatter<<<2048, 256, 0, stream>>>(row, col, cnt0, cnt1, colbuf, E, rpx, nhalf);
  k_norm<<<(N+255)/256, 256, 0, stream>>>(cnt0, cnt1, norm, rnorm, N);

  k_xemb<<<(N+63)/64, 256, 0, stream>>>(x, pe, Wtb, b_xemb, norm, bfA, N);

  int lgrid = 8 * ((N + 31)/32);
  // L0: bfA -> st0
  k_p0<<<lgrid, 256, 0, stream>>>(bfA, cnt0, colbuf, partial, N);
  k_p1<<<lgrid, 256, 0, stream>>>(bfA, cnt1, colbuf, partial, norm, st0, 0,
                                  nullptr, nullptr, nullptr, nullptr, nullptr, N);
  // L1: st0 -> bfA
  k_p0<<<lgrid, 256, 0, stream>>>(st0, cnt0, colbuf, partial, N);
  k_p1<<<lgrid, 256, 0, stream>>>(st0, cnt1, colbuf, partial, norm, bfA, 0,
                                  nullptr, nullptr, nullptr, nullptr, nullptr, N);
  // L2: bfA -> out (JK fused with st0, bfA)
  k_p0<<<lgrid, 256, 0, stream>>>(bfA, cnt0, colbuf, partial, N);
  k_p1<<<lgrid, 256, 0, stream>>>(bfA, cnt1, colbuf, partial, norm, nullptr, 1,
                                  st0, bfA, rnorm, jkp, out, N);
}

// Round 17
// 1080.670 us; speedup vs baseline: 1.0183x; 1.0183x over previous
//
#include <hip/hip_runtime.h>

constexpr int IN   = 256;
constexpr int H    = 256;
constexpr int STR  = 60;
constexpr int NLOC = 8;
constexpr int CW   = 32;      // columns per state slab (8 slabs of 32 cols = one 64B line)
constexpr int KP   = 288;     // padded K for MFMA (264 -> 288)
constexpr int CAP  = 96;      // fixed CSR row capacity (Poisson(32): P(deg>96)~1e-25)
constexpr int BSTR = 40;      // LDS B-stage col stride (ushorts)

typedef float    f32x4 __attribute__((ext_vector_type(4)));
typedef float    f32x2 __attribute__((ext_vector_type(2)));
typedef unsigned u32x2 __attribute__((ext_vector_type(2)));
typedef short    bf16x8 __attribute__((ext_vector_type(8)));

__device__ __forceinline__ float bflo(unsigned u) { return __uint_as_float(u << 16); }
__device__ __forceinline__ float bfhi(unsigned u) { return __uint_as_float(u & 0xFFFF0000u); }
__device__ __forceinline__ unsigned short f2bf(float f) {
  unsigned u = __float_as_uint(f);
  u += 0x7FFF + ((u >> 16) & 1);          // round-to-nearest-even
  return (unsigned short)(u >> 16);
}

// ---------------- pos_embedding (also zeroes cnt) ----------------
__global__ void k_pe(const float* __restrict__ pos_emb, const float* __restrict__ lap_pe,
                     const float* __restrict__ W, const float* __restrict__ b,
                     float* __restrict__ pe, int* __restrict__ cnt, int n) {
  int i = blockIdx.x*blockDim.x + threadIdx.x;
  if (i >= n) return;
  cnt[i] = 0;
  float acc[NLOC];
  #pragma unroll
  for (int j = 0; j < NLOC; ++j) acc[j] = b[j];
  const float* pr = pos_emb + (size_t)i*STR;
  for (int k = 0; k < STR; ++k) {
    float v = pr[k];
    #pragma unroll
    for (int j = 0; j < NLOC; ++j) acc[j] += v*W[k*NLOC + j];
  }
  const float* lr = lap_pe + (size_t)i*(STR-1);
  for (int k = 0; k < STR-1; ++k) {
    float v = lr[k];
    #pragma unroll
    for (int j = 0; j < NLOC; ++j) acc[j] += v*W[(STR+k)*NLOC + j];
  }
  float* po = pe + (size_t)i*NLOC;
  #pragma unroll
  for (int j = 0; j < NLOC; ++j) po[j] = acc[j];
}

// ---------------- W transpose+convert: Wtb[col][KP] bf16, zero-padded ----------------
__global__ void k_wtb(const float* __restrict__ W, unsigned short* __restrict__ Wtb) {
  int col = blockIdx.x;                 // 0..255
  for (int k = threadIdx.x; k < KP; k += blockDim.x) {
    float v = (k < IN + NLOC) ? W[(size_t)k*H + col] : 0.f;
    Wtb[(size_t)col*KP + k] = f2bf(v);
  }
}

// ---------------- XCD-partitioned scatter into fixed-stride CSR (R14-proven) ----------------
__global__ void k_scatter(const int* __restrict__ row, const int* __restrict__ col,
                          int* __restrict__ cnt, int* __restrict__ colbuf,
                          int E, int rpx) {
  int xcd = blockIdx.x & 7;
  int rlo = xcd * rpx;
  int rhi = rlo + rpx;
  int nblk = gridDim.x >> 3;
  int bi = blockIdx.x >> 3;
  int stride = (nblk * blockDim.x) << 2;
  int i0 = (bi*blockDim.x + threadIdx.x) << 2;
  for (int i = i0; i + 4 <= E; i += stride) {
    int4 rr = *(const int4*)&row[i];
    if (rr.x >= rlo && rr.x < rhi) {
      int p = atomicAdd(&cnt[rr.x], 1);
      if (p < CAP) colbuf[(size_t)rr.x*CAP + p] = col[i];
    }
    if (rr.y >= rlo && rr.y < rhi) {
      int p = atomicAdd(&cnt[rr.y], 1);
      if (p < CAP) colbuf[(size_t)rr.y*CAP + p] = col[i+1];
    }
    if (rr.z >= rlo && rr.z < rhi) {
      int p = atomicAdd(&cnt[rr.z], 1);
      if (p < CAP) colbuf[(size_t)rr.z*CAP + p] = col[i+2];
    }
    if (rr.w >= rlo && rr.w < rhi) {
      int p = atomicAdd(&cnt[rr.w], 1);
      if (p < CAP) colbuf[(size_t)rr.w*CAP + p] = col[i+3];
    }
  }
  if (blockIdx.x == 0 && threadIdx.x < 4) {
    int base = E & ~3;
    int i = base + threadIdx.x;
    if (i < E) {
      int r = row[i];
      if (r >= rlo && r < rhi) {
        int p = atomicAdd(&cnt[r], 1);
        if (p < CAP) colbuf[(size_t)r*CAP + p] = col[i];
      }
    }
  }
}

// ---------------- norm + rnorm from counts ----------------
__global__ void k_norm(const int* __restrict__ cnt, float* __restrict__ norm,
                       float* __restrict__ rnorm, int n) {
  int i = blockIdx.x*blockDim.x + threadIdx.x;
  if (i >= n) return;
  int d = cnt[i]; if (d > CAP) d = CAP;
  float s = 1.0f + (float)d;
  norm[i]  = rsqrtf(s);
  rnorm[i] = sqrtf(s);
}

// ---------------- xemb via MFMA bf16, LDS-staged B (R15-proven), 8-slab output ----------------
__global__ __launch_bounds__(256) void k_xemb(
    const float* __restrict__ x, const float* __restrict__ pe,
    const unsigned short* __restrict__ Wtb, const float* __restrict__ bvec,
    const float* __restrict__ norm, unsigned short* __restrict__ st, int n) {
  __shared__ unsigned short Bs[256*BSTR];    // 20 KB
  int t = threadIdx.x;
  int wv = t >> 6, l = t & 63;
  int lr = l & 15, kb = l >> 4;
  int i0 = blockIdx.x*64 + wv*16;
  int arow = i0 + lr;
  int ar = (arow < n) ? arow : n - 1;

  f32x4 acc[16];
  #pragma unroll
  for (int cb = 0; cb < 16; ++cb) acc[cb] = (f32x4){0.f,0.f,0.f,0.f};

  #pragma unroll
  for (int ks = 0; ks < 9; ++ks) {
    int k0 = ks*32;
    __syncthreads();
    {
      const unsigned short* wsrc = Wtb + (size_t)t*KP + k0;
      unsigned short* wdst = Bs + t*BSTR;
      #pragma unroll
      for (int m = 0; m < 4; ++m)
        *(bf16x8*)(wdst + m*8) = *(const bf16x8*)(wsrc + m*8);
    }
    float a8[8];
    if (ks < 8) {
      const float* ap = x + (size_t)ar*IN + k0 + kb*8;
      float4 v0 = *(const float4*)ap;
      float4 v1 = *(const float4*)(ap + 4);
      a8[0]=v0.x; a8[1]=v0.y; a8[2]=v0.z; a8[3]=v0.w;
      a8[4]=v1.x; a8[5]=v1.y; a8[6]=v1.z; a8[7]=v1.w;
    } else if (kb == 0) {
      const float* ap = pe + (size_t)ar*NLOC;
      float4 v0 = *(const float4*)ap;
      float4 v1 = *(const float4*)(ap + 4);
      a8[0]=v0.x; a8[1]=v0.y; a8[2]=v0.z; a8[3]=v0.w;
      a8[4]=v1.x; a8[5]=v1.y; a8[6]=v1.z; a8[7]=v1.w;
    } else {
      #pragma unroll
      for (int j = 0; j < 8; ++j) a8[j] = 0.f;
    }
    bf16x8 af;
    #pragma unroll
    for (int j = 0; j < 8; ++j) af[j] = (short)f2bf(a8[j]);
    __syncthreads();
    #pragma unroll
    for (int cb = 0; cb < 16; ++cb) {
      bf16x8 bf = *(const bf16x8*)(Bs + (cb*16 + lr)*BSTR + kb*8);
      acc[cb] = __builtin_amdgcn_mfma_f32_16x16x32_bf16(af, bf, acc[cb], 0, 0, 0);
    }
  }

  int r0 = i0 + kb*4;
  float nrm[4];
  #pragma unroll
  for (int j = 0; j < 4; ++j) {
    int rr = r0 + j;
    nrm[j] = (rr < n) ? norm[rr] : 0.f;
  }
  size_t slabsz = (size_t)n * CW;
  #pragma unroll
  for (int cb = 0; cb < 16; ++cb) {
    int col = cb*16 + lr;
    float bias = bvec[col];
    unsigned short* sp = st + (size_t)(col >> 5)*slabsz + (col & 31);
    #pragma unroll
    for (int j = 0; j < 4; ++j) {
      int rr = r0 + j;
      if (rr < n)
        sp[(size_t)rr*CW] = f2bf(nrm[j]*(acc[cb][j] + bias));
    }
  }
}

// ---------------- 8-slab single-pass layer (wave = 4 rows x 16 lanes x uint) ----------------
// Per gather instr: 4 segments x 64 B (full lines) — R15's segment count, half the
// per-XCD working set (6.4 MB). Arithmetic bit-identical to R15 per column.
// !last: st_next = bf16(norm^2 * (agg+self))
//  last: out = rnorm * (j0*st0 + j1*st1 + j2*norm^2*(agg+self))   [JK fused]
__global__ __launch_bounds__(256) void k_layer(
    const unsigned short* __restrict__ st, const int* __restrict__ cnt,
    const int* __restrict__ colbuf, const float* __restrict__ norm,
    unsigned short* __restrict__ st_next, int last,
    const unsigned short* __restrict__ s0buf, const unsigned short* __restrict__ s1buf,
    const float* __restrict__ rnorm, const float* __restrict__ jkp,
    float* __restrict__ out, int n, int nrb16) {
  int w = blockIdx.x;
  int chunk = w & 7;                     // slab 0..7, one XCD per slab
  int rb = w >> 3;                       // row-block (16 rows)
  if (rb >= nrb16) return;
  int t = threadIdx.x;
  int wave = t >> 6, lane = t & 63;
  int li = lane & 15, rs = lane >> 4;    // uint slot / row-sub (0..3)
  int r = rb*16 + wave*4 + rs;
  if (r >= n) return;
  size_t slabu = (size_t)n * 16;         // uints per slab (32 cols = 16 uint)
  const unsigned* gb = (const unsigned*)st + (size_t)chunk*slabu + li;
  int deg = cnt[r]; if (deg > CAP) deg = CAP;
  int start = r*CAP, end = start + deg;
  float2 acc = make_float2(0.f, 0.f);
  int j = start;
  for (; j + 4 <= end; j += 4) {
    int4 cc = *(const int4*)&colbuf[j];            // 16B-aligned (start = r*96)
    unsigned v0 = gb[(size_t)cc.x*16];
    unsigned v1 = gb[(size_t)cc.y*16];
    unsigned v2 = gb[(size_t)cc.z*16];
    unsigned v3 = gb[(size_t)cc.w*16];
    acc.x += (bflo(v0)+bflo(v1)) + (bflo(v2)+bflo(v3));
    acc.y += (bfhi(v0)+bfhi(v1)) + (bfhi(v2)+bfhi(v3));
  }
  for (; j < end; ++j) {
    unsigned v0 = gb[(size_t)colbuf[j]*16];
    acc.x += bflo(v0); acc.y += bfhi(v0);
  }
  // self term
  unsigned sv = gb[(size_t)r*16];
  acc.x += bflo(sv); acc.y += bfhi(sv);
  float nr = norm[r];
  float n2 = nr*nr;
  if (!last) {
    unsigned short s0 = f2bf(n2*acc.x);
    unsigned short s1 = f2bf(n2*acc.y);
    unsigned pk = (unsigned)s0 | ((unsigned)s1 << 16);
    __builtin_nontemporal_store(pk,
        (unsigned*)st_next + (size_t)chunk*slabu + (size_t)r*16 + li);
  } else {
    size_t off = (size_t)chunk*slabu + (size_t)r*16 + li;
    unsigned a = ((const unsigned*)s0buf)[off];
    unsigned b = ((const unsigned*)s1buf)[off];
    float rn = rnorm[r];
    float j0 = jkp[0], j1 = jkp[1], j2 = jkp[2];
    f32x2 o;
    o.x = rn*(j0*bflo(a) + j1*bflo(b) + j2*(n2*acc.x));
    o.y = rn*(j0*bfhi(a) + j1*bfhi(b) + j2*(n2*acc.y));
    __builtin_nontemporal_store(o, (f32x2*)(out + (size_t)r*H + chunk*CW + li*2));
  }
}

extern "C" void kernel_launch(void* const* d_in, const int* in_sizes, int n_in,
                              void* d_out, int out_size, void* d_ws, size_t ws_size,
                              hipStream_t stream) {
  const float* x       = (const float*)d_in[0];
  const float* pos_emb = (const float*)d_in[1];
  const float* lap_pe  = (const float*)d_in[2];
  const float* W_pos   = (const float*)d_in[3];
  const float* b_pos   = (const float*)d_in[4];
  const float* W_xemb  = (const float*)d_in[5];
  const float* b_xemb  = (const float*)d_in[6];
  const float* jkp     = (const float*)d_in[7];
  const int*   row     = (const int*)d_in[8];
  const int*   col     = (const int*)d_in[9];
  int N = in_sizes[0] / IN;
  int E = in_sizes[8];
  float* out = (float*)d_out;

  char* p = (char*)d_ws;
  auto alloc = [&](size_t bytes) {
    char* r = p; p += (bytes + 255) & ~(size_t)255; return r;
  };
  unsigned short* bfA = (unsigned short*)alloc((size_t)N*H*2);  // xemb / st1
  unsigned short* st0 = (unsigned short*)alloc((size_t)N*H*2);  // layer0 out
  int*   colbuf = (int*)  alloc((size_t)N*CAP*4);               // 38.4 MB
  float* pe     = (float*)alloc((size_t)N*NLOC*4);
  int*   cnt    = (int*)  alloc((size_t)N*4);
  float* norm   = (float*)alloc((size_t)N*4);
  float* rnorm  = (float*)alloc((size_t)N*4);
  unsigned short* Wtb = (unsigned short*)alloc((size_t)H*KP*2);

  k_pe<<<(N+255)/256, 256, 0, stream>>>(pos_emb, lap_pe, W_pos, b_pos, pe, cnt, N);
  k_wtb<<<H, 128, 0, stream>>>(W_xemb, Wtb);
  int rpx = (N + 7)/8;                        // rows per XCD slice
  k_scatter<<<2048, 256, 0, stream>>>(row, col, cnt, colbuf, E, rpx);
  k_norm<<<(N+255)/256, 256, 0, stream>>>(cnt, norm, rnorm, N);

  k_xemb<<<(N+63)/64, 256, 0, stream>>>(x, pe, Wtb, b_xemb, norm, bfA, N);

  int nrb16 = (N + 15)/16;
  int lgrid = 8 * nrb16;
  k_layer<<<lgrid, 256, 0, stream>>>(bfA, cnt, colbuf, norm, st0, 0,
                                     nullptr, nullptr, nullptr, nullptr, nullptr, N, nrb16);
  k_layer<<<lgrid, 256, 0, stream>>>(st0, cnt, colbuf, norm, bfA, 0,
                                     nullptr, nullptr, nullptr, nullptr, nullptr, N, nrb16);
  k_layer<<<lgrid, 256, 0, stream>>>(bfA, cnt, colbuf, norm, nullptr, 1,
                                     st0, bfA, rnorm, jkp, out, N, nrb16);
}

// Round 19
// 1031.401 us; speedup vs baseline: 1.0670x; 1.0478x over previous
//
#include <hip/hip_runtime.h>

constexpr int IN   = 256;
constexpr int H    = 256;
constexpr int STR  = 60;
constexpr int NLOC = 8;
constexpr int CW   = 64;      // columns per state slab (4 slabs of 64 cols)
constexpr int KP   = 288;     // padded K for MFMA (264 -> 288)
constexpr int CAP  = 96;      // fixed CSR row capacity (Poisson(32): P(deg>96)~1e-25)
constexpr int BSTR = 40;      // LDS B-stage col stride (ushorts)

typedef float    f32x4 __attribute__((ext_vector_type(4)));
typedef unsigned u32x2 __attribute__((ext_vector_type(2)));
typedef short    bf16x8 __attribute__((ext_vector_type(8)));
typedef int      i32x4 __attribute__((ext_vector_type(4)));

__device__ __forceinline__ float bflo(unsigned u) { return __uint_as_float(u << 16); }
__device__ __forceinline__ float bfhi(unsigned u) { return __uint_as_float(u & 0xFFFF0000u); }
__device__ __forceinline__ unsigned short f2bf(float f) {
  unsigned u = __float_as_uint(f);
  u += 0x7FFF + ((u >> 16) & 1);          // round-to-nearest-even
  return (unsigned short)(u >> 16);
}

// ---------------- pos_embedding (also zeroes cnt) ----------------
__global__ void k_pe(const float* __restrict__ pos_emb, const float* __restrict__ lap_pe,
                     const float* __restrict__ W, const float* __restrict__ b,
                     float* __restrict__ pe, int* __restrict__ cnt, int n) {
  int i = blockIdx.x*blockDim.x + threadIdx.x;
  if (i >= n) return;
  cnt[i] = 0;
  float acc[NLOC];
  #pragma unroll
  for (int j = 0; j < NLOC; ++j) acc[j] = b[j];
  const float* pr = pos_emb + (size_t)i*STR;
  for (int k = 0; k < STR; ++k) {
    float v = pr[k];
    #pragma unroll
    for (int j = 0; j < NLOC; ++j) acc[j] += v*W[k*NLOC + j];
  }
  const float* lr = lap_pe + (size_t)i*(STR-1);
  for (int k = 0; k < STR-1; ++k) {
    float v = lr[k];
    #pragma unroll
    for (int j = 0; j < NLOC; ++j) acc[j] += v*W[(STR+k)*NLOC + j];
  }
  float* po = pe + (size_t)i*NLOC;
  #pragma unroll
  for (int j = 0; j < NLOC; ++j) po[j] = acc[j];
}

// ---------------- W transpose+convert: Wtb[col][KP] bf16, zero-padded ----------------
__global__ void k_wtb(const float* __restrict__ W, unsigned short* __restrict__ Wtb) {
  int col = blockIdx.x;                 // 0..255
  for (int k = threadIdx.x; k < KP; k += blockDim.x) {
    float v = (k < IN + NLOC) ? W[(size_t)k*H + col] : 0.f;
    Wtb[(size_t)col*KP + k] = f2bf(v);
  }
}

// ---------------- XCD-partitioned scatter into fixed-stride CSR (nt streams) ----------------
__global__ void k_scatter(const int* __restrict__ row, const int* __restrict__ col,
                          int* __restrict__ cnt, int* __restrict__ colbuf,
                          int E, int rpx) {
  int xcd = blockIdx.x & 7;
  int rlo = xcd * rpx;
  int rhi = rlo + rpx;
  int nblk = gridDim.x >> 3;
  int bi = blockIdx.x >> 3;
  int stride = (nblk * blockDim.x) << 2;
  int i0 = (bi*blockDim.x + threadIdx.x) << 2;
  for (int i = i0; i + 4 <= E; i += stride) {
    i32x4 rr = __builtin_nontemporal_load((const i32x4*)&row[i]);
    if (rr[0] >= rlo && rr[0] < rhi) {
      int p = atomicAdd(&cnt[rr[0]], 1);
      if (p < CAP) colbuf[(size_t)rr[0]*CAP + p] = __builtin_nontemporal_load(&col[i]);
    }
    if (rr[1] >= rlo && rr[1] < rhi) {
      int p = atomicAdd(&cnt[rr[1]], 1);
      if (p < CAP) colbuf[(size_t)rr[1]*CAP + p] = __builtin_nontemporal_load(&col[i+1]);
    }
    if (rr[2] >= rlo && rr[2] < rhi) {
      int p = atomicAdd(&cnt[rr[2]], 1);
      if (p < CAP) colbuf[(size_t)rr[2]*CAP + p] = __builtin_nontemporal_load(&col[i+2]);
    }
    if (rr[3] >= rlo && rr[3] < rhi) {
      int p = atomicAdd(&cnt[rr[3]], 1);
      if (p < CAP) colbuf[(size_t)rr[3]*CAP + p] = __builtin_nontemporal_load(&col[i+3]);
    }
  }
  if (blockIdx.x == 0 && threadIdx.x < 4) {
    int base = E & ~3;
    int i = base + threadIdx.x;
    if (i < E) {
      int r = row[i];
      if (r >= rlo && r < rhi) {
        int p = atomicAdd(&cnt[r], 1);
        if (p < CAP) colbuf[(size_t)r*CAP + p] = col[i];
      }
    }
  }
}

// ---------------- norm + rnorm from counts ----------------
__global__ void k_norm(const int* __restrict__ cnt, float* __restrict__ norm,
                       float* __restrict__ rnorm, int n) {
  int i = blockIdx.x*blockDim.x + threadIdx.x;
  if (i >= n) return;
  int d = cnt[i]; if (d > CAP) d = CAP;
  float s = 1.0f + (float)d;
  norm[i]  = rsqrtf(s);
  rnorm[i] = sqrtf(s);
}

// ---------------- xemb via MFMA bf16, LDS-staged B (R15-proven), 4-slab output ----------------
__global__ __launch_bounds__(256) void k_xemb(
    const float* __restrict__ x, const float* __restrict__ pe,
    const unsigned short* __restrict__ Wtb, const float* __restrict__ bvec,
    const float* __restrict__ norm, unsigned short* __restrict__ st, int n) {
  __shared__ unsigned short Bs[256*BSTR];    // 20 KB
  int t = threadIdx.x;
  int wv = t >> 6, l = t & 63;
  int lr = l & 15, kb = l >> 4;
  int i0 = blockIdx.x*64 + wv*16;
  int arow = i0 + lr;
  int ar = (arow < n) ? arow : n - 1;

  f32x4 acc[16];
  #pragma unroll
  for (int cb = 0; cb < 16; ++cb) acc[cb] = (f32x4){0.f,0.f,0.f,0.f};

  #pragma unroll
  for (int ks = 0; ks < 9; ++ks) {
    int k0 = ks*32;
    __syncthreads();
    {
      const unsigned short* wsrc = Wtb + (size_t)t*KP + k0;
      unsigned short* wdst = Bs + t*BSTR;
      #pragma unroll
      for (int m = 0; m < 4; ++m)
        *(bf16x8*)(wdst + m*8) = *(const bf16x8*)(wsrc + m*8);
    }
    float a8[8];
    if (ks < 8) {
      const float* ap = x + (size_t)ar*IN + k0 + kb*8;
      float4 v0 = *(const float4*)ap;
      float4 v1 = *(const float4*)(ap + 4);
      a8[0]=v0.x; a8[1]=v0.y; a8[2]=v0.z; a8[3]=v0.w;
      a8[4]=v1.x; a8[5]=v1.y; a8[6]=v1.z; a8[7]=v1.w;
    } else if (kb == 0) {
      const float* ap = pe + (size_t)ar*NLOC;
      float4 v0 = *(const float4*)ap;
      float4 v1 = *(const float4*)(ap + 4);
      a8[0]=v0.x; a8[1]=v0.y; a8[2]=v0.z; a8[3]=v0.w;
      a8[4]=v1.x; a8[5]=v1.y; a8[6]=v1.z; a8[7]=v1.w;
    } else {
      #pragma unroll
      for (int j = 0; j < 8; ++j) a8[j] = 0.f;
    }
    bf16x8 af;
    #pragma unroll
    for (int j = 0; j < 8; ++j) af[j] = (short)f2bf(a8[j]);
    __syncthreads();
    #pragma unroll
    for (int cb = 0; cb < 16; ++cb) {
      bf16x8 bf = *(const bf16x8*)(Bs + (cb*16 + lr)*BSTR + kb*8);
      acc[cb] = __builtin_amdgcn_mfma_f32_16x16x32_bf16(af, bf, acc[cb], 0, 0, 0);
    }
  }

  int r0 = i0 + kb*4;
  float nrm[4];
  #pragma unroll
  for (int j = 0; j < 4; ++j) {
    int rr = r0 + j;
    nrm[j] = (rr < n) ? norm[rr] : 0.f;
  }
  size_t slabsz = (size_t)n * CW;
  #pragma unroll
  for (int cb = 0; cb < 16; ++cb) {
    int col = cb*16 + lr;
    float bias = bvec[col];
    unsigned short* sp = st + (size_t)(col >> 6)*slabsz + (col & 63);
    #pragma unroll
    for (int j = 0; j < 4; ++j) {
      int rr = r0 + j;
      if (rr < n)
        sp[(size_t)rr*CW] = f2bf(nrm[j]*(acc[cb][j] + bias));
    }
  }
}

// ---------------- 4-slab chunked layer (R15-proven; nt colbuf loads) ----------------
// !last: st_next = bf16(norm^2 * (agg+self))
//  last: out = rnorm * (j0*st0 + j1*st1 + j2*norm^2*(agg+self))   [JK fused]
__global__ __launch_bounds__(256) void k_layer(
    const unsigned short* __restrict__ st, const int* __restrict__ cnt,
    const int* __restrict__ colbuf, const float* __restrict__ norm,
    unsigned short* __restrict__ st_next, int last,
    const unsigned short* __restrict__ s0buf, const unsigned short* __restrict__ s1buf,
    const float* __restrict__ rnorm, const float* __restrict__ jkp,
    float* __restrict__ out, int n, int nrb16) {
  int w = blockIdx.x;
  int xcd = w & 7;
  int chunk = xcd >> 1;                  // slab 0..3 (2 XCDs per slab)
  int rb = (w >> 3)*2 + (xcd & 1);       // row-block (16 rows)
  if (rb >= nrb16) return;
  int t = threadIdx.x;
  int wave = t >> 6, lane = t & 63;
  int li = lane & 15, rs = lane >> 4;    // lane-in-row / row-sub (0..3)
  int r = rb*16 + wave*4 + rs;
  if (r >= n) return;
  size_t slabu2 = (size_t)n * 16;        // uint2 per slab (64 cols = 16 uint2)
  const uint2* gb = (const uint2*)st + (size_t)chunk*slabu2 + li;
  int deg = cnt[r]; if (deg > CAP) deg = CAP;
  int start = r*CAP, end = start + deg;
  float4 acc = make_float4(0.f,0.f,0.f,0.f);
  int j = start;
  for (; j + 4 <= end; j += 4) {
    i32x4 cc = __builtin_nontemporal_load((const i32x4*)&colbuf[j]);  // 16B-aligned
    uint2 v0 = gb[(size_t)cc[0]*16];
    uint2 v1 = gb[(size_t)cc[1]*16];
    uint2 v2 = gb[(size_t)cc[2]*16];
    uint2 v3 = gb[(size_t)cc[3]*16];
    acc.x += (bflo(v0.x)+bflo(v1.x)) + (bflo(v2.x)+bflo(v3.x));
    acc.y += (bfhi(v0.x)+bfhi(v1.x)) + (bfhi(v2.x)+bfhi(v3.x));
    acc.z += (bflo(v0.y)+bflo(v1.y)) + (bflo(v2.y)+bflo(v3.y));
    acc.w += (bfhi(v0.y)+bfhi(v1.y)) + (bfhi(v2.y)+bfhi(v3.y));
  }
  for (; j < end; ++j) {
    int c0 = __builtin_nontemporal_load(&colbuf[j]);
    uint2 v0 = gb[(size_t)c0*16];
    acc.x += bflo(v0.x); acc.y += bfhi(v0.x);
    acc.z += bflo(v0.y); acc.w += bfhi(v0.y);
  }
  // self term
  uint2 sv = gb[(size_t)r*16];
  acc.x += bflo(sv.x); acc.y += bfhi(sv.x);
  acc.z += bflo(sv.y); acc.w += bfhi(sv.y);
  float nr = norm[r];
  float n2 = nr*nr;
  if (!last) {
    unsigned short s0 = f2bf(n2*acc.x);
    unsigned short s1 = f2bf(n2*acc.y);
    unsigned short s2 = f2bf(n2*acc.z);
    unsigned short s3 = f2bf(n2*acc.w);
    u32x2 pk;
    pk.x = (unsigned)s0 | ((unsigned)s1 << 16);
    pk.y = (unsigned)s2 | ((unsigned)s3 << 16);
    __builtin_nontemporal_store(pk,
        (u32x2*)st_next + (size_t)chunk*slabu2 + (size_t)r*16 + li);
  } else {
    size_t off = (size_t)chunk*slabu2 + (size_t)r*16 + li;
    uint2 a = ((const uint2*)s0buf)[off];
    uint2 b = ((const uint2*)s1buf)[off];
    float rn = rnorm[r];
    float j0 = jkp[0], j1 = jkp[1], j2 = jkp[2];
    f32x4 o;
    o.x = rn*(j0*bflo(a.x) + j1*bflo(b.x) + j2*(n2*acc.x));
    o.y = rn*(j0*bfhi(a.x) + j1*bfhi(b.x) + j2*(n2*acc.y));
    o.z = rn*(j0*bflo(a.y) + j1*bflo(b.y) + j2*(n2*acc.z));
    o.w = rn*(j0*bfhi(a.y) + j1*bfhi(b.y) + j2*(n2*acc.w));
    __builtin_nontemporal_store(o, (f32x4*)(out + (size_t)r*H + chunk*CW + li*4));
  }
}

extern "C" void kernel_launch(void* const* d_in, const int* in_sizes, int n_in,
                              void* d_out, int out_size, void* d_ws, size_t ws_size,
                              hipStream_t stream) {
  const float* x       = (const float*)d_in[0];
  const float* pos_emb = (const float*)d_in[1];
  const float* lap_pe  = (const float*)d_in[2];
  const float* W_pos   = (const float*)d_in[3];
  const float* b_pos   = (const float*)d_in[4];
  const float* W_xemb  = (const float*)d_in[5];
  const float* b_xemb  = (const float*)d_in[6];
  const float* jkp     = (const float*)d_in[7];
  const int*   row     = (const int*)d_in[8];
  const int*   col     = (const int*)d_in[9];
  int N = in_sizes[0] / IN;
  int E = in_sizes[8];
  float* out = (float*)d_out;

  char* p = (char*)d_ws;
  auto alloc = [&](size_t bytes) {
    char* r = p; p += (bytes + 255) & ~(size_t)255; return r;
  };
  unsigned short* bfA = (unsigned short*)alloc((size_t)N*H*2);  // xemb / st1
  unsigned short* st0 = (unsigned short*)alloc((size_t)N*H*2);  // layer0 out
  int*   colbuf = (int*)  alloc((size_t)N*CAP*4);               // 38.4 MB
  float* pe     = (float*)alloc((size_t)N*NLOC*4);
  int*   cnt    = (int*)  alloc((size_t)N*4);
  float* norm   = (float*)alloc((size_t)N*4);
  float* rnorm  = (float*)alloc((size_t)N*4);
  unsigned short* Wtb = (unsigned short*)alloc((size_t)H*KP*2);

  k_pe<<<(N+255)/256, 256, 0, stream>>>(pos_emb, lap_pe, W_pos, b_pos, pe, cnt, N);
  k_wtb<<<H, 128, 0, stream>>>(W_xemb, Wtb);
  int rpx = (N + 7)/8;                        // rows per XCD slice
  k_scatter<<<2048, 256, 0, stream>>>(row, col, cnt, colbuf, E, rpx);
  k_norm<<<(N+255)/256, 256, 0, stream>>>(cnt, norm, rnorm, N);

  k_xemb<<<(N+63)/64, 256, 0, stream>>>(x, pe, Wtb, b_xemb, norm, bfA, N);

  int nrb16 = (N + 15)/16;
  int lgrid = 8 * ((nrb16 + 1)/2);
  k_layer<<<lgrid, 256, 0, stream>>>(bfA, cnt, colbuf, norm, st0, 0,
                                     nullptr, nullptr, nullptr, nullptr, nullptr, N, nrb16);
  k_layer<<<lgrid, 256, 0, stream>>>(st0, cnt, colbuf, norm, bfA, 0,
                                     nullptr, nullptr, nullptr, nullptr, nullptr, N, nrb16);
  k_layer<<<lgrid, 256, 0, stream>>>(bfA, cnt, colbuf, norm, nullptr, 1,
                                     st0, bfA, rnorm, jkp, out, N, nrb16);
}

// Round 20
// 848.831 us; speedup vs baseline: 1.2965x; 1.2151x over previous
//
#include <hip/hip_runtime.h>

constexpr int IN   = 256;
constexpr int H    = 256;
constexpr int STR  = 60;
constexpr int NLOC = 8;
constexpr int CW   = 64;      // columns per state slab (4 slabs of 64 cols)
constexpr int KP   = 288;     // padded K for MFMA (264 -> 288)
constexpr int CAP  = 96;      // fixed CSR row capacity (Poisson(32): P(deg>96)~1e-25)
constexpr int BSTR = 40;      // LDS B-stage col stride (ushorts)

typedef float    f32x4 __attribute__((ext_vector_type(4)));
typedef unsigned u32x2 __attribute__((ext_vector_type(2)));
typedef short    bf16x8 __attribute__((ext_vector_type(8)));

__device__ __forceinline__ float bflo(unsigned u) { return __uint_as_float(u << 16); }
__device__ __forceinline__ float bfhi(unsigned u) { return __uint_as_float(u & 0xFFFF0000u); }
__device__ __forceinline__ unsigned short f2bf(float f) {
  unsigned u = __float_as_uint(f);
  u += 0x7FFF + ((u >> 16) & 1);          // round-to-nearest-even
  return (unsigned short)(u >> 16);
}

// ---------------- pos_embedding (also zeroes cnt) ----------------
__global__ void k_pe(const float* __restrict__ pos_emb, const float* __restrict__ lap_pe,
                     const float* __restrict__ W, const float* __restrict__ b,
                     float* __restrict__ pe, int* __restrict__ cnt, int n) {
  int i = blockIdx.x*blockDim.x + threadIdx.x;
  if (i >= n) return;
  cnt[i] = 0;
  float acc[NLOC];
  #pragma unroll
  for (int j = 0; j < NLOC; ++j) acc[j] = b[j];
  const float* pr = pos_emb + (size_t)i*STR;
  for (int k = 0; k < STR; ++k) {
    float v = pr[k];
    #pragma unroll
    for (int j = 0; j < NLOC; ++j) acc[j] += v*W[k*NLOC + j];
  }
  const float* lr = lap_pe + (size_t)i*(STR-1);
  for (int k = 0; k < STR-1; ++k) {
    float v = lr[k];
    #pragma unroll
    for (int j = 0; j < NLOC; ++j) acc[j] += v*W[(STR+k)*NLOC + j];
  }
  float* po = pe + (size_t)i*NLOC;
  #pragma unroll
  for (int j = 0; j < NLOC; ++j) po[j] = acc[j];
}

// ---------------- W transpose+convert: Wtb[col][KP] bf16, zero-padded ----------------
__global__ void k_wtb(const float* __restrict__ W, unsigned short* __restrict__ Wtb) {
  int col = blockIdx.x;                 // 0..255
  for (int k = threadIdx.x; k < KP; k += blockDim.x) {
    float v = (k < IN + NLOC) ? W[(size_t)k*H + col] : 0.f;
    Wtb[(size_t)col*KP + k] = f2bf(v);
  }
}

// ---------------- XCD-partitioned scatter into fixed-stride CSR (R14/R15-proven) ----------------
__global__ void k_scatter(const int* __restrict__ row, const int* __restrict__ col,
                          int* __restrict__ cnt, int* __restrict__ colbuf,
                          int E, int rpx) {
  int xcd = blockIdx.x & 7;
  int rlo = xcd * rpx;
  int rhi = rlo + rpx;
  int nblk = gridDim.x >> 3;
  int bi = blockIdx.x >> 3;
  int stride = (nblk * blockDim.x) << 2;
  int i0 = (bi*blockDim.x + threadIdx.x) << 2;
  for (int i = i0; i + 4 <= E; i += stride) {
    int4 rr = *(const int4*)&row[i];
    if (rr.x >= rlo && rr.x < rhi) {
      int p = atomicAdd(&cnt[rr.x], 1);
      if (p < CAP) colbuf[(size_t)rr.x*CAP + p] = col[i];
    }
    if (rr.y >= rlo && rr.y < rhi) {
      int p = atomicAdd(&cnt[rr.y], 1);
      if (p < CAP) colbuf[(size_t)rr.y*CAP + p] = col[i+1];
    }
    if (rr.z >= rlo && rr.z < rhi) {
      int p = atomicAdd(&cnt[rr.z], 1);
      if (p < CAP) colbuf[(size_t)rr.z*CAP + p] = col[i+2];
    }
    if (rr.w >= rlo && rr.w < rhi) {
      int p = atomicAdd(&cnt[rr.w], 1);
      if (p < CAP) colbuf[(size_t)rr.w*CAP + p] = col[i+3];
    }
  }
  if (blockIdx.x == 0 && threadIdx.x < 4) {
    int base = E & ~3;
    int i = base + threadIdx.x;
    if (i < E) {
      int r = row[i];
      if (r >= rlo && r < rhi) {
        int p = atomicAdd(&cnt[r], 1);
        if (p < CAP) colbuf[(size_t)r*CAP + p] = col[i];
      }
    }
  }
}

// ---------------- norm + rnorm from counts ----------------
__global__ void k_norm(const int* __restrict__ cnt, float* __restrict__ norm,
                       float* __restrict__ rnorm, int n) {
  int i = blockIdx.x*blockDim.x + threadIdx.x;
  if (i >= n) return;
  int d = cnt[i]; if (d > CAP) d = CAP;
  float s = 1.0f + (float)d;
  norm[i]  = rsqrtf(s);
  rnorm[i] = sqrtf(s);
}

// ---------------- xemb via MFMA bf16, LDS-staged B (R15-proven), 4-slab output ----------------
__global__ __launch_bounds__(256) void k_xemb(
    const float* __restrict__ x, const float* __restrict__ pe,
    const unsigned short* __restrict__ Wtb, const float* __restrict__ bvec,
    const float* __restrict__ norm, unsigned short* __restrict__ st, int n) {
  __shared__ unsigned short Bs[256*BSTR];    // 20 KB
  int t = threadIdx.x;
  int wv = t >> 6, l = t & 63;
  int lr = l & 15, kb = l >> 4;
  int i0 = blockIdx.x*64 + wv*16;
  int arow = i0 + lr;
  int ar = (arow < n) ? arow : n - 1;

  f32x4 acc[16];
  #pragma unroll
  for (int cb = 0; cb < 16; ++cb) acc[cb] = (f32x4){0.f,0.f,0.f,0.f};

  #pragma unroll
  for (int ks = 0; ks < 9; ++ks) {
    int k0 = ks*32;
    __syncthreads();
    {
      const unsigned short* wsrc = Wtb + (size_t)t*KP + k0;
      unsigned short* wdst = Bs + t*BSTR;
      #pragma unroll
      for (int m = 0; m < 4; ++m)
        *(bf16x8*)(wdst + m*8) = *(const bf16x8*)(wsrc + m*8);
    }
    float a8[8];
    if (ks < 8) {
      const float* ap = x + (size_t)ar*IN + k0 + kb*8;
      float4 v0 = *(const float4*)ap;
      float4 v1 = *(const float4*)(ap + 4);
      a8[0]=v0.x; a8[1]=v0.y; a8[2]=v0.z; a8[3]=v0.w;
      a8[4]=v1.x; a8[5]=v1.y; a8[6]=v1.z; a8[7]=v1.w;
    } else if (kb == 0) {
      const float* ap = pe + (size_t)ar*NLOC;
      float4 v0 = *(const float4*)ap;
      float4 v1 = *(const float4*)(ap + 4);
      a8[0]=v0.x; a8[1]=v0.y; a8[2]=v0.z; a8[3]=v0.w;
      a8[4]=v1.x; a8[5]=v1.y; a8[6]=v1.z; a8[7]=v1.w;
    } else {
      #pragma unroll
      for (int j = 0; j < 8; ++j) a8[j] = 0.f;
    }
    bf16x8 af;
    #pragma unroll
    for (int j = 0; j < 8; ++j) af[j] = (short)f2bf(a8[j]);
    __syncthreads();
    #pragma unroll
    for (int cb = 0; cb < 16; ++cb) {
      bf16x8 bf = *(const bf16x8*)(Bs + (cb*16 + lr)*BSTR + kb*8);
      acc[cb] = __builtin_amdgcn_mfma_f32_16x16x32_bf16(af, bf, acc[cb], 0, 0, 0);
    }
  }

  int r0 = i0 + kb*4;
  float nrm[4];
  #pragma unroll
  for (int j = 0; j < 4; ++j) {
    int rr = r0 + j;
    nrm[j] = (rr < n) ? norm[rr] : 0.f;
  }
  size_t slabsz = (size_t)n * CW;
  #pragma unroll
  for (int cb = 0; cb < 16; ++cb) {
    int col = cb*16 + lr;
    float bias = bvec[col];
    unsigned short* sp = st + (size_t)(col >> 6)*slabsz + (col & 63);
    #pragma unroll
    for (int j = 0; j < 4; ++j) {
      int rr = r0 + j;
      if (rr < n)
        sp[(size_t)rr*CW] = f2bf(nrm[j]*(acc[cb][j] + bias));
    }
  }
}

// ---------------- 4-slab chunked layer (R15-proven, plain loads) ----------------
// !last: st_next = bf16(norm^2 * (agg+self))
//  last: out = rnorm * (j0*st0 + j1*st1 + j2*norm^2*(agg+self))   [JK fused]
__global__ __launch_bounds__(256) void k_layer(
    const unsigned short* __restrict__ st, const int* __restrict__ cnt,
    const int* __restrict__ colbuf, const float* __restrict__ norm,
    unsigned short* __restrict__ st_next, int last,
    const unsigned short* __restrict__ s0buf, const unsigned short* __restrict__ s1buf,
    const float* __restrict__ rnorm, const float* __restrict__ jkp,
    float* __restrict__ out, int n, int nrb16) {
  int w = blockIdx.x;
  int xcd = w & 7;
  int chunk = xcd >> 1;                  // slab 0..3 (2 XCDs per slab)
  int rb = (w >> 3)*2 + (xcd & 1);       // row-block (16 rows)
  if (rb >= nrb16) return;
  int t = threadIdx.x;
  int wave = t >> 6, lane = t & 63;
  int li = lane & 15, rs = lane >> 4;    // lane-in-row / row-sub (0..3)
  int r = rb*16 + wave*4 + rs;
  if (r >= n) return;
  size_t slabu2 = (size_t)n * 16;        // uint2 per slab (64 cols = 16 uint2)
  const uint2* gb = (const uint2*)st + (size_t)chunk*slabu2 + li;
  int deg = cnt[r]; if (deg > CAP) deg = CAP;
  int start = r*CAP, end = start + deg;
  float4 acc = make_float4(0.f,0.f,0.f,0.f);
  int j = start;
  for (; j + 4 <= end; j += 4) {
    int4 cc = *(const int4*)&colbuf[j];            // 16B-aligned (start = r*96)
    uint2 v0 = gb[(size_t)cc.x*16];
    uint2 v1 = gb[(size_t)cc.y*16];
    uint2 v2 = gb[(size_t)cc.z*16];
    uint2 v3 = gb[(size_t)cc.w*16];
    acc.x += (bflo(v0.x)+bflo(v1.x)) + (bflo(v2.x)+bflo(v3.x));
    acc.y += (bfhi(v0.x)+bfhi(v1.x)) + (bfhi(v2.x)+bfhi(v3.x));
    acc.z += (bflo(v0.y)+bflo(v1.y)) + (bflo(v2.y)+bflo(v3.y));
    acc.w += (bfhi(v0.y)+bfhi(v1.y)) + (bfhi(v2.y)+bfhi(v3.y));
  }
  for (; j < end; ++j) {
    int c0 = colbuf[j];
    uint2 v0 = gb[(size_t)c0*16];
    acc.x += bflo(v0.x); acc.y += bfhi(v0.x);
    acc.z += bflo(v0.y); acc.w += bfhi(v0.y);
  }
  // self term
  uint2 sv = gb[(size_t)r*16];
  acc.x += bflo(sv.x); acc.y += bfhi(sv.x);
  acc.z += bflo(sv.y); acc.w += bfhi(sv.y);
  float nr = norm[r];
  float n2 = nr*nr;
  if (!last) {
    unsigned short s0 = f2bf(n2*acc.x);
    unsigned short s1 = f2bf(n2*acc.y);
    unsigned short s2 = f2bf(n2*acc.z);
    unsigned short s3 = f2bf(n2*acc.w);
    u32x2 pk;
    pk.x = (unsigned)s0 | ((unsigned)s1 << 16);
    pk.y = (unsigned)s2 | ((unsigned)s3 << 16);
    __builtin_nontemporal_store(pk,
        (u32x2*)st_next + (size_t)chunk*slabu2 + (size_t)r*16 + li);
  } else {
    size_t off = (size_t)chunk*slabu2 + (size_t)r*16 + li;
    uint2 a = ((const uint2*)s0buf)[off];
    uint2 b = ((const uint2*)s1buf)[off];
    float rn = rnorm[r];
    float j0 = jkp[0], j1 = jkp[1], j2 = jkp[2];
    f32x4 o;
    o.x = rn*(j0*bflo(a.x) + j1*bflo(b.x) + j2*(n2*acc.x));
    o.y = rn*(j0*bfhi(a.x) + j1*bfhi(b.x) + j2*(n2*acc.y));
    o.z = rn*(j0*bflo(a.y) + j1*bflo(b.y) + j2*(n2*acc.z));
    o.w = rn*(j0*bfhi(a.y) + j1*bfhi(b.y) + j2*(n2*acc.w));
    __builtin_nontemporal_store(o, (f32x4*)(out + (size_t)r*H + chunk*CW + li*4));
  }
}

extern "C" void kernel_launch(void* const* d_in, const int* in_sizes, int n_in,
                              void* d_out, int out_size, void* d_ws, size_t ws_size,
                              hipStream_t stream) {
  const float* x       = (const float*)d_in[0];
  const float* pos_emb = (const float*)d_in[1];
  const float* lap_pe  = (const float*)d_in[2];
  const float* W_pos   = (const float*)d_in[3];
  const float* b_pos   = (const float*)d_in[4];
  const float* W_xemb  = (const float*)d_in[5];
  const float* b_xemb  = (const float*)d_in[6];
  const float* jkp     = (const float*)d_in[7];
  const int*   row     = (const int*)d_in[8];
  const int*   col     = (const int*)d_in[9];
  int N = in_sizes[0] / IN;
  int E = in_sizes[8];
  float* out = (float*)d_out;

  char* p = (char*)d_ws;
  auto alloc = [&](size_t bytes) {
    char* r = p; p += (bytes + 255) & ~(size_t)255; return r;
  };
  unsigned short* bfA = (unsigned short*)alloc((size_t)N*H*2);  // xemb / st1
  unsigned short* st0 = (unsigned short*)alloc((size_t)N*H*2);  // layer0 out
  int*   colbuf = (int*)  alloc((size_t)N*CAP*4);               // 38.4 MB
  float* pe     = (float*)alloc((size_t)N*NLOC*4);
  int*   cnt    = (int*)  alloc((size_t)N*4);
  float* norm   = (float*)alloc((size_t)N*4);
  float* rnorm  = (float*)alloc((size_t)N*4);
  unsigned short* Wtb = (unsigned short*)alloc((size_t)H*KP*2);

  k_pe<<<(N+255)/256, 256, 0, stream>>>(pos_emb, lap_pe, W_pos, b_pos, pe, cnt, N);
  k_wtb<<<H, 128, 0, stream>>>(W_xemb, Wtb);
  int rpx = (N + 7)/8;                        // rows per XCD slice
  k_scatter<<<2048, 256, 0, stream>>>(row, col, cnt, colbuf, E, rpx);
  k_norm<<<(N+255)/256, 256, 0, stream>>>(cnt, norm, rnorm, N);

  k_xemb<<<(N+63)/64, 256, 0, stream>>>(x, pe, Wtb, b_xemb, norm, bfA, N);

  int nrb16 = (N + 15)/16;
  int lgrid = 8 * ((nrb16 + 1)/2);
  k_layer<<<lgrid, 256, 0, stream>>>(bfA, cnt, colbuf, norm, st0, 0,
                                     nullptr, nullptr, nullptr, nullptr, nullptr, N, nrb16);
  k_layer<<<lgrid, 256, 0, stream>>>(st0, cnt, colbuf, norm, bfA, 0,
                                     nullptr, nullptr, nullptr, nullptr, nullptr, N, nrb16);
  k_layer<<<lgrid, 256, 0, stream>>>(bfA, cnt, colbuf, norm, nullptr, 1,
                                     st0, bfA, rnorm, jkp, out, N, nrb16);
}